// Round 3
// baseline (415.657 us; speedup 1.0000x reference)
//
#include <hip/hip_runtime.h>
#include <math.h>

// Problem constants
#define BB 16
#define CHN 256
#define TT 576
#define NHD 8
#define DHD 32
#define SCALE_F 0.17677669529663687f  // 1/sqrt(32)

// XOR chunk swizzle: element (row p, depth d) -> byte-conflict-free float offset
__device__ __forceinline__ int SW(int p, int d) {
    return ((((d >> 2) ^ (p & 7)) << 2) | (d & 3));
}

// ---------------------------------------------------------------------------
// Kernel A: QKV 1x1-conv GEMM.  out[b][o][i] = sum_c w[o][c]*x[b][c][i] + bias[o]
// Grid: 16 b * 16 i-tiles(36) * 3 o-chunks(256) = 768 blocks, 256 threads.
// W tile staged TRANSPOSED [kc][oo] (stride 260) so each thread reads its 4 o
// as one ds_read_b128.
// ---------------------------------------------------------------------------
__global__ __launch_bounds__(256) void qkv_gemm_k(const float* __restrict__ x,
                                                  const float* __restrict__ w,
                                                  const float* __restrict__ bias,
                                                  float* __restrict__ out) {
    __shared__ float ws[32 * 260];   // [kc][oo], stride 260 (16B-aligned, odd/4 banks)
    __shared__ float xs[32 * 36];    // [kc][ii]
    int orig = blockIdx.x;
    int wg = (orig & 7) * 96 + (orig >> 3);      // XCD-chunked swizzle (768 % 8 == 0)
    int b = wg / 48;
    int rem = wg % 48;
    int it = rem / 3, oh = rem % 3;
    int o0 = oh * 256, i0 = it * 36;
    int tid = threadIdx.x;
    int og = tid >> 2, itg = tid & 3;            // thread owns 4 o x 9 i

    float acc[4][9];
#pragma unroll
    for (int r = 0; r < 4; ++r)
#pragma unroll
        for (int s = 0; s < 9; ++s) acc[r][s] = 0.f;

    for (int kt = 0; kt < 8; ++kt) {
        // stage W tile transposed: load float4 along kc, scatter to [kc][oo]
        for (int idx4 = tid; idx4 < 2048; idx4 += 256) {
            int oo = idx4 >> 3, kc4 = (idx4 & 7) * 4;
            const float4 v = *reinterpret_cast<const float4*>(&w[(o0 + oo) * 256 + kt * 32 + kc4]);
            ws[(kc4 + 0) * 260 + oo] = v.x;
            ws[(kc4 + 1) * 260 + oo] = v.y;
            ws[(kc4 + 2) * 260 + oo] = v.z;
            ws[(kc4 + 3) * 260 + oo] = v.w;
        }
        // stage X tile (32 x 36)
        for (int idx4 = tid; idx4 < 288; idx4 += 256) {
            int kc = idx4 / 9, ii4 = idx4 % 9;
            const float4 v = *reinterpret_cast<const float4*>(&x[(b * 256 + kt * 32 + kc) * 576 + i0 + ii4 * 4]);
            *reinterpret_cast<float4*>(&xs[kc * 36 + ii4 * 4]) = v;
        }
        __syncthreads();
#pragma unroll 8
        for (int kc = 0; kc < 32; ++kc) {
            float4 wr = *reinterpret_cast<const float4*>(&ws[kc * 260 + og * 4]);
            float xv[9];
#pragma unroll
            for (int s = 0; s < 9; ++s) xv[s] = xs[kc * 36 + itg * 9 + s];
#pragma unroll
            for (int s = 0; s < 9; ++s) {
                acc[0][s] += wr.x * xv[s];
                acc[1][s] += wr.y * xv[s];
                acc[2][s] += wr.z * xv[s];
                acc[3][s] += wr.w * xv[s];
            }
        }
        __syncthreads();
    }
#pragma unroll
    for (int r = 0; r < 4; ++r) {
        int o = o0 + og * 4 + r;
        float bb = bias[o];
#pragma unroll
        for (int s = 0; s < 9; ++s)
            out[(b * 768 + o) * 576 + i0 + itg * 9 + s] = acc[r][s] + bb;
    }
}

// ---------------------------------------------------------------------------
// Kernel C: fused relative-position attention.
// Grid: 256 blocks (16 b x 16 i-tiles of 36), 256 threads, 150 KB LDS.
// LDS layouts put d contiguous (float4 reads) with XOR chunk swizzle.
//   logits s[n][i][jj] = (q.k + bd[n][i][jj%24]) * SCALE
//   attn = softmax over n (8 heads)           <- per reference, axis=1!
//   out[n][d][i] = sum_jj attn*v + sum_c colsum[n][i][c]*(rh_v+rw_v)[j(i,c)-1][n][d]
// ---------------------------------------------------------------------------
__global__ __launch_bounds__(256) void attn_k(const float* __restrict__ qkv,
                                              const float* __restrict__ rh_k,
                                              const float* __restrict__ rw_k,
                                              const float* __restrict__ rh_v,
                                              const float* __restrict__ rw_v,
                                              float* __restrict__ att_out) {
    __shared__ float qs[12288];   // q [n][iw=48][d=32] swizzled; epilogue reuse: (rh_v+rw_v) stride 260 (12220)
    __shared__ float kvs[12288];  // K [n][c=24][d] @0, V same @6144, swizzled; pre-loop reuse: (rh_k+rw_k) stride 260
    __shared__ float bds[6912];   // bd [n][i=36][c=24]
    __shared__ float ats[6912];   // logits/probs [n][i][c]; end: colsum

    int orig = blockIdx.x;
    int wg = (orig & 7) * 32 + (orig >> 3);      // XCD swizzle: XCD x gets b in {2x,2x+1} (K/V L2 locality)
    int b = wg >> 4, it = wg & 15;
    int i0 = it * 36;
    int tid = threadIdx.x;
    const float* qb = qkv + (size_t)b * 768 * 576;

    // ---- load q window rows [i0, i0+48) (clipped) transposed into qs ----
    for (int idx4 = tid; idx4 < 3072; idx4 += 256) {
        int o = idx4 / 12, iw4 = (idx4 % 12) * 4;
        int n = o >> 5, d = o & 31;
        int gi = i0 + iw4;
        float4 v;
        if (gi + 3 < 576) {
            v = *reinterpret_cast<const float4*>(&qb[o * 576 + gi]);
        } else {
            v.x = (gi + 0 < 576) ? qb[o * 576 + gi + 0] : 0.f;
            v.y = (gi + 1 < 576) ? qb[o * 576 + gi + 1] : 0.f;
            v.z = (gi + 2 < 576) ? qb[o * 576 + gi + 2] : 0.f;
            v.w = (gi + 3 < 576) ? qb[o * 576 + gi + 3] : 0.f;
        }
        qs[n * 1536 + (iw4 + 0) * 32 + SW(iw4 + 0, d)] = v.x;
        qs[n * 1536 + (iw4 + 1) * 32 + SW(iw4 + 1, d)] = v.y;
        qs[n * 1536 + (iw4 + 2) * 32 + SW(iw4 + 2, d)] = v.z;
        qs[n * 1536 + (iw4 + 3) * 32 + SW(iw4 + 3, d)] = v.w;
    }
    // ---- load rh_k + rw_k into kvs (stride 260: 16B-aligned rows) ----
    for (int idx = tid; idx < 12032; idx += 256) {
        int j = idx >> 8, nd = idx & 255;
        kvs[j * 260 + nd] = rh_k[idx] + rw_k[idx];
    }
    __syncthreads();

    // thread ids
    int n1 = tid >> 5;
    int g1 = tid & 31, ig1 = g1 >> 3, jg1 = g1 & 7;   // phase-1: 9 i x 3 c
    int dg = (tid >> 2) & 7, ig2 = tid & 3;           // phase-2: 4 d x 9 i
    int d0 = dg * 4, ib = ig2 * 9;

    // ---- bd tile: bds[n][i][c] = dot32(q[:, isrc], (rh_k+rw_k)[j-1]) ----
#pragma unroll
    for (int r = 0; r < 9; ++r) {
        int i_loc = ig1 * 9 + r;
        int f0 = 576 + 47 * (i0 + i_loc);
#pragma unroll
        for (int s = 0; s < 3; ++s) {
            int c = jg1 * 3 + s;
            int f = f0 + c;
            int j = f % 48;
            float val = 0.f;
            if (j > 0) {
                int isl = f / 48 - i0;   // proven in [0,48)
                int bq = n1 * 1536 + isl * 32;
                int swz = isl & 7;
                int br = (j - 1) * 260 + n1 * 32;
#pragma unroll
                for (int dq = 0; dq < 8; ++dq) {
                    float4 qv = *reinterpret_cast<const float4*>(&qs[bq + (((dq ^ swz)) << 2)]);
                    float4 rv = *reinterpret_cast<const float4*>(&kvs[br + dq * 4]);
                    val += qv.x * rv.x + qv.y * rv.y + qv.z * rv.z + qv.w * rv.w;
                }
            }
            bds[n1 * 864 + i_loc * 24 + c] = val;
        }
    }
    __syncthreads();

    // persistent per-thread state
    float cs[4][8];      // colsum for softmax-owned (i,c) pairs
#pragma unroll
    for (int k = 0; k < 4; ++k)
#pragma unroll
        for (int nn = 0; nn < 8; ++nn) cs[k][nn] = 0.f;
    float acc[4][9];     // output acc: (d0..d0+3) x (ib..ib+8)
#pragma unroll
    for (int r = 0; r < 4; ++r)
#pragma unroll
        for (int s = 0; s < 9; ++s) acc[r][s] = 0.f;

    for (int tt = 0; tt < 24; ++tt) {
        // ---- stage K,V tiles transposed [n][c][d] ----
        const float* kb = qb + 256 * 576 + tt * 24;
        const float* vb = qb + 512 * 576 + tt * 24;
        for (int idx4 = tid; idx4 < 1536; idx4 += 256) {
            int o = idx4 / 6, c4 = (idx4 % 6) * 4;
            int n = o >> 5, d = o & 31;
            float4 kv = *reinterpret_cast<const float4*>(&kb[o * 576 + c4]);
            float4 vv = *reinterpret_cast<const float4*>(&vb[o * 576 + c4]);
            int base = n * 768;
            kvs[base + (c4 + 0) * 32 + SW(c4 + 0, d)] = kv.x;
            kvs[base + (c4 + 1) * 32 + SW(c4 + 1, d)] = kv.y;
            kvs[base + (c4 + 2) * 32 + SW(c4 + 2, d)] = kv.z;
            kvs[base + (c4 + 3) * 32 + SW(c4 + 3, d)] = kv.w;
            kvs[6144 + base + (c4 + 0) * 32 + SW(c4 + 0, d)] = vv.x;
            kvs[6144 + base + (c4 + 1) * 32 + SW(c4 + 1, d)] = vv.y;
            kvs[6144 + base + (c4 + 2) * 32 + SW(c4 + 2, d)] = vv.z;
            kvs[6144 + base + (c4 + 3) * 32 + SW(c4 + 3, d)] = vv.w;
        }
        __syncthreads();

        // ---- phase 1: logits (q.k + bd)*SCALE -> ats (float4 dot over d) ----
        {
            float a[9][3];
#pragma unroll
            for (int r = 0; r < 9; ++r)
#pragma unroll
                for (int s = 0; s < 3; ++s)
                    a[r][s] = bds[n1 * 864 + (ig1 * 9 + r) * 24 + jg1 * 3 + s];
#pragma unroll
            for (int dq = 0; dq < 8; ++dq) {
                float4 qv[9], kv[3];
#pragma unroll
                for (int r = 0; r < 9; ++r) {
                    int iw = ig1 * 9 + r;
                    qv[r] = *reinterpret_cast<const float4*>(&qs[n1 * 1536 + iw * 32 + ((dq ^ (iw & 7)) << 2)]);
                }
#pragma unroll
                for (int s = 0; s < 3; ++s) {
                    int c = jg1 * 3 + s;
                    kv[s] = *reinterpret_cast<const float4*>(&kvs[n1 * 768 + c * 32 + ((dq ^ (c & 7)) << 2)]);
                }
#pragma unroll
                for (int r = 0; r < 9; ++r)
#pragma unroll
                    for (int s = 0; s < 3; ++s)
                        a[r][s] += qv[r].x * kv[s].x + qv[r].y * kv[s].y +
                                   qv[r].z * kv[s].z + qv[r].w * kv[s].w;
            }
#pragma unroll
            for (int r = 0; r < 9; ++r)
#pragma unroll
                for (int s = 0; s < 3; ++s)
                    ats[n1 * 864 + (ig1 * 9 + r) * 24 + jg1 * 3 + s] = a[r][s] * SCALE_F;
        }
        __syncthreads();

        // ---- softmax over the 8 heads per (i,c); accumulate colsum ----
#pragma unroll
        for (int k = 0; k < 4; ++k) {
            int p = k * 256 + tid;
            if (p < 864) {
                float xv[8];
#pragma unroll
                for (int nn = 0; nn < 8; ++nn) xv[nn] = ats[nn * 864 + p];
                float m = xv[0];
#pragma unroll
                for (int nn = 1; nn < 8; ++nn) m = fmaxf(m, xv[nn]);
                float e[8], ssum = 0.f;
#pragma unroll
                for (int nn = 0; nn < 8; ++nn) { e[nn] = __expf(xv[nn] - m); ssum += e[nn]; }
                float inv = 1.0f / ssum;
#pragma unroll
                for (int nn = 0; nn < 8; ++nn) {
                    float aa = e[nn] * inv;
                    ats[nn * 864 + p] = aa;
                    cs[k][nn] += aa;
                }
            }
        }
        __syncthreads();

        // ---- phase 2: acc += attn @ V (V float4 over d) ----
#pragma unroll 4
        for (int c = 0; c < 24; ++c) {
            float4 vv = *reinterpret_cast<const float4*>(&kvs[6144 + n1 * 768 + c * 32 + ((dg ^ (c & 7)) << 2)]);
            const float* abase = &ats[n1 * 864 + ib * 24 + c];
#pragma unroll
            for (int s = 0; s < 9; ++s) {
                float pv = abase[s * 24];
                acc[0][s] += vv.x * pv;
                acc[1][s] += vv.y * pv;
                acc[2][s] += vv.z * pv;
                acc[3][s] += vv.w * pv;
            }
        }
        __syncthreads();
    }

    // ---- colsum -> ats; (rh_v+rw_v) -> qs (stride 260) ----
#pragma unroll
    for (int k = 0; k < 4; ++k) {
        int p = k * 256 + tid;
        if (p < 864) {
#pragma unroll
            for (int nn = 0; nn < 8; ++nn) ats[nn * 864 + p] = cs[k][nn];
        }
    }
    for (int idx = tid; idx < 12032; idx += 256) {
        int j = idx >> 8, nd = idx & 255;
        qs[j * 260 + nd] = rh_v[idx] + rw_v[idx];
    }
    __syncthreads();

    // ---- positional-value epilogue: acc += colsum[n][i][c] * rhwv[j-1][n][d0..d0+3] ----
#pragma unroll
    for (int s = 0; s < 9; ++s) {
        int i_loc = ib + s;
        int f0 = 576 + 47 * (i0 + i_loc);
#pragma unroll 4
        for (int c = 0; c < 24; ++c) {
            int f = f0 + c;
            int j = f % 48;
            if (j > 0) {
                float wv = ats[n1 * 864 + i_loc * 24 + c];
                float4 rr = *reinterpret_cast<const float4*>(&qs[(j - 1) * 260 + n1 * 32 + d0]);
                acc[0][s] += wv * rr.x;
                acc[1][s] += wv * rr.y;
                acc[2][s] += wv * rr.z;
                acc[3][s] += wv * rr.w;
            }
        }
    }

    // ---- write out: att_out[b][n*32+d][i] ----
#pragma unroll
    for (int r = 0; r < 4; ++r)
#pragma unroll
        for (int s = 0; s < 9; ++s)
            att_out[((size_t)b * 256 + n1 * 32 + d0 + r) * 576 + i0 + ib + s] = acc[r][s];
}

// ---------------------------------------------------------------------------
// Kernel D: FC 1x1-conv GEMM + bias + residual (W tile transposed like A).
// Writes y directly into d_out; GroupNorm then runs in place.
// Grid: 256 blocks (16 b x 16 i-tiles of 36), 256 threads.
// ---------------------------------------------------------------------------
__global__ __launch_bounds__(256) void fc_k(const float* __restrict__ att,
                                            const float* __restrict__ w,
                                            const float* __restrict__ bias,
                                            const float* __restrict__ x,
                                            float* __restrict__ y) {
    __shared__ float ws[32 * 260];
    __shared__ float as[32 * 36];
    int orig = blockIdx.x;
    int wg = (orig & 7) * 32 + (orig >> 3);
    int b = wg >> 4, it = wg & 15;
    int i0 = it * 36;
    int tid = threadIdx.x;
    int og = tid >> 2, itg = tid & 3;

    float acc[4][9];
#pragma unroll
    for (int r = 0; r < 4; ++r)
#pragma unroll
        for (int s = 0; s < 9; ++s) acc[r][s] = 0.f;

    for (int kt = 0; kt < 8; ++kt) {
        for (int idx4 = tid; idx4 < 2048; idx4 += 256) {
            int oo = idx4 >> 3, kc4 = (idx4 & 7) * 4;
            const float4 v = *reinterpret_cast<const float4*>(&w[oo * 256 + kt * 32 + kc4]);
            ws[(kc4 + 0) * 260 + oo] = v.x;
            ws[(kc4 + 1) * 260 + oo] = v.y;
            ws[(kc4 + 2) * 260 + oo] = v.z;
            ws[(kc4 + 3) * 260 + oo] = v.w;
        }
        for (int idx4 = tid; idx4 < 288; idx4 += 256) {
            int kc = idx4 / 9, ii4 = idx4 % 9;
            const float4 v = *reinterpret_cast<const float4*>(&att[(b * 256 + kt * 32 + kc) * 576 + i0 + ii4 * 4]);
            *reinterpret_cast<float4*>(&as[kc * 36 + ii4 * 4]) = v;
        }
        __syncthreads();
#pragma unroll 8
        for (int kc = 0; kc < 32; ++kc) {
            float4 wr = *reinterpret_cast<const float4*>(&ws[kc * 260 + og * 4]);
            float xv[9];
#pragma unroll
            for (int s = 0; s < 9; ++s) xv[s] = as[kc * 36 + itg * 9 + s];
#pragma unroll
            for (int s = 0; s < 9; ++s) {
                acc[0][s] += wr.x * xv[s];
                acc[1][s] += wr.y * xv[s];
                acc[2][s] += wr.z * xv[s];
                acc[3][s] += wr.w * xv[s];
            }
        }
        __syncthreads();
    }
#pragma unroll
    for (int r = 0; r < 4; ++r) {
        int o = og * 4 + r;
        float bb = bias[o];
#pragma unroll
        for (int s = 0; s < 9; ++s) {
            int gidx = (b * 256 + o) * 576 + i0 + itg * 9 + s;
            y[gidx] = acc[r][s] + bb + x[gidx];
        }
    }
}

// ---------------------------------------------------------------------------
// Kernel E: GroupNorm(16 groups), IN PLACE on d_out.
// Grid: 256 blocks (16 b x 16 groups), 256 threads, wave-shuffle reduction.
// Each thread loads its full region into registers before any write -> in-place safe.
// ---------------------------------------------------------------------------
__global__ __launch_bounds__(256) void gn_k(float* __restrict__ y,
                                            const float* __restrict__ gw,
                                            const float* __restrict__ gb) {
    __shared__ double psum[4], psq[4];
    __shared__ float stat[2];
    int b = blockIdx.x >> 4, grp = blockIdx.x & 15;
    size_t base = ((size_t)b * 256 + grp * 16) * 576;
    int tid = threadIdx.x;
    int lane = tid & 63, wid = tid >> 6;

    float4 vals[9];
    double s = 0.0, s2 = 0.0;
#pragma unroll
    for (int k = 0; k < 9; ++k) {
        float4 v = *reinterpret_cast<const float4*>(&y[base + (size_t)(k * 256 + tid) * 4]);
        vals[k] = v;
        s += (double)v.x + (double)v.y + (double)v.z + (double)v.w;
        s2 += (double)v.x * v.x + (double)v.y * v.y + (double)v.z * v.z + (double)v.w * v.w;
    }
#pragma unroll
    for (int off = 32; off > 0; off >>= 1) {
        s += __shfl_down(s, off);
        s2 += __shfl_down(s2, off);
    }
    if (lane == 0) { psum[wid] = s; psq[wid] = s2; }
    __syncthreads();
    if (tid == 0) {
        double ts = psum[0] + psum[1] + psum[2] + psum[3];
        double tq = psq[0] + psq[1] + psq[2] + psq[3];
        double mean = ts * (1.0 / 9216.0);
        double var = tq * (1.0 / 9216.0) - mean * mean;
        stat[0] = (float)mean;
        stat[1] = (float)(1.0 / sqrt(var + 1e-5));
    }
    __syncthreads();
    float mf = stat[0], rstd = stat[1];
#pragma unroll
    for (int k = 0; k < 9; ++k) {
        int idx4 = k * 256 + tid;
        int ch = grp * 16 + idx4 / 144;          // 144 float4 per channel
        float wv = gw[ch], bv = gb[ch];
        float4 v = vals[k];
        float4 r;
        r.x = (v.x - mf) * rstd * wv + bv;
        r.y = (v.y - mf) * rstd * wv + bv;
        r.z = (v.z - mf) * rstd * wv + bv;
        r.w = (v.w - mf) * rstd * wv + bv;
        *reinterpret_cast<float4*>(&y[base + (size_t)idx4 * 4]) = r;
    }
}

// ---------------------------------------------------------------------------
extern "C" void kernel_launch(void* const* d_in, const int* in_sizes, int n_in,
                              void* d_out, int out_size, void* d_ws, size_t ws_size,
                              hipStream_t stream) {
    const float* x     = (const float*)d_in[0];
    const float* qkv_w = (const float*)d_in[1];
    const float* qkv_b = (const float*)d_in[2];
    const float* rh_k  = (const float*)d_in[3];
    const float* rw_k  = (const float*)d_in[4];
    const float* rh_v  = (const float*)d_in[5];
    const float* rw_v  = (const float*)d_in[6];
    const float* fc_w  = (const float*)d_in[7];
    const float* fc_b  = (const float*)d_in[8];
    const float* gn_w  = (const float*)d_in[9];
    const float* gn_b  = (const float*)d_in[10];
    float* out = (float*)d_out;

    float* qkv = (float*)d_ws;            // 16*768*576 = 7,077,888 floats (27.0 MB)
    float* att = qkv + 7077888;           // 16*256*576 = 2,359,296 floats (9.0 MB)

    qkv_gemm_k<<<768, 256, 0, stream>>>(x, qkv_w, qkv_b, qkv);
    attn_k<<<256, 256, 0, stream>>>(qkv, rh_k, rw_k, rh_v, rw_v, att);
    fc_k<<<256, 256, 0, stream>>>(att, fc_w, fc_b, x, out);   // y -> d_out
    gn_k<<<256, 256, 0, stream>>>(out, gn_w, gn_b);           // in-place GN
}